// Round 1
// baseline (168329.602 us; speedup 1.0000x reference)
//
#include <hip/hip_runtime.h>
#include <math.h>

// Problem constants (from reference): B=32, T=1024, C=1024
#define CC    1024
#define CC2   2048
#define BB    32
#define TT    1024
#define NBLK  256      // persistent grid: <= #CUs so all blocks co-resident (barrier-safe)
#define NTHR  512      // 8 waves/block
#define LNEPS 1e-5f

// Workspace layout (float indices)
#define WS_H    0        // h state: 32*1024
#define WS_Y    32768    // y:       32*2048
#define WS_Y2   98304    // y2:      32*1024
#define WS_BARF 131072   // barrier uints (2048): leaves [g*32], root [1024], gen [1056]
// total ws: (131072 + 2048) * 4B = 532 KB

__global__ void rpe_init(float* __restrict__ ws) {
    unsigned* bar = (unsigned*)(ws + WS_BARF);
    for (int i = blockIdx.x * blockDim.x + threadIdx.x; i < 32768 + 2048;
         i += gridDim.x * blockDim.x) {
        if (i < 32768) ws[WS_H + i] = 0.0f;   // h0 = 0
        else           bar[i - 32768] = 0u;   // barrier counters = 0 (ws is poisoned 0xAA)
    }
}

// Two-level monotonic grid barrier. Grid=256 blocks: 32 leaf groups of 8.
// Monotonic counters -> no reset races. Release: __threadfence (L2 wb) before arrive.
// Acquire: relaxed spin on gen, then __threadfence (cache inv) by all threads.
__device__ __forceinline__ void gridbar(unsigned* bar, unsigned phase) {
    __syncthreads();  // drains all block stores (vmcnt0 before s_barrier)
    if (threadIdx.x == 0) {
        __threadfence();  // push this XCD's L2 to coherence point
        const unsigned g = (unsigned)blockIdx.x >> 3;
        unsigned v = __hip_atomic_fetch_add(&bar[g * 32u], 1u,
                        __ATOMIC_RELAXED, __HIP_MEMORY_SCOPE_AGENT) + 1u;
        if (v == phase * 8u) {
            unsigned r = __hip_atomic_fetch_add(&bar[1024], 1u,
                            __ATOMIC_RELAXED, __HIP_MEMORY_SCOPE_AGENT) + 1u;
            if (r == phase * 32u) {
                __hip_atomic_fetch_add(&bar[1056], 1u,
                    __ATOMIC_RELEASE, __HIP_MEMORY_SCOPE_AGENT);
            }
        }
        while (__hip_atomic_load(&bar[1056], __ATOMIC_RELAXED,
                                 __HIP_MEMORY_SCOPE_AGENT) < phase) {
            __builtin_amdgcn_s_sleep(2);
        }
    }
    __syncthreads();
    __threadfence();  // invalidate stale L1/L2 before reading other blocks' data
}

__device__ __forceinline__ float gelu_exact(float a) {
    return 0.5f * a * (1.0f + erff(a * 0.70710678118654752440f));
}

extern "C" __global__ void __launch_bounds__(NTHR)
rpe_main(const float* __restrict__ x,  const float* __restrict__ Wa,
         const float* __restrict__ ba, const float* __restrict__ Wb,
         const float* __restrict__ bb, const float* __restrict__ gamma,
         const float* __restrict__ beta, float* __restrict__ out,
         float* __restrict__ ws)
{
    float*    h_ws  = ws + WS_H;
    float*    y_ws  = ws + WS_Y;
    float*    y2_ws = ws + WS_Y2;
    unsigned* bar   = (unsigned*)(ws + WS_BARF);

    const int tid  = threadIdx.x;
    const int blk  = blockIdx.x;
    const int wv   = tid >> 6;     // wave 0..7 (K-split)
    const int lane = tid & 63;

    __shared__ float red[2048];    // cross-wave partial reduction (8 KB)
    __shared__ float redC[16];     // LN cross-wave sums

    // Phase A lane mapping: 8 j-lanes x 8 b-lanes; each lane accumulates 4 batches.
    const int jlA = lane & 7, blA = lane >> 3;
    const int j0A = blk * 8;                 // 256 blocks * 8 = 2048 j-columns
    // Phase B lane mapping: 4 i-lanes x 16 b-lanes; each lane accumulates 2 batches.
    const int ilB = lane & 3, blB = lane >> 2;
    const int i0B = blk * 4;                 // 256 blocks * 4 = 1024 i-columns

    unsigned ph = 0;

    for (int t = 0; t < TT; ++t) {
        // ============ Phase A: y[b][j] = gelu( sum_k z[b][k]*Wa[j][k] + ba[j] ) ====
        // z = [h (k<1024) || x_t (k>=1024)]. Wave wv owns k in [wv*256, wv*256+256):
        // waves 0..3 read h_ws, waves 4..7 read x directly (no concat materialized).
        {
            const int j = j0A + jlA;
            const float* wrow = Wa + (size_t)j * CC2 + wv * 256;
            const int bbase = blA * 4;
            const float *z0, *z1, *z2, *z3;
            if (wv < 4) {
                const float* hb = h_ws + wv * 256;
                z0 = hb + (size_t)(bbase + 0) * CC;
                z1 = hb + (size_t)(bbase + 1) * CC;
                z2 = hb + (size_t)(bbase + 2) * CC;
                z3 = hb + (size_t)(bbase + 3) * CC;
            } else {
                const float* xb = x + (size_t)t * CC + (size_t)(wv - 4) * 256;
                z0 = xb + (size_t)(bbase + 0) * TT * CC;
                z1 = xb + (size_t)(bbase + 1) * TT * CC;
                z2 = xb + (size_t)(bbase + 2) * TT * CC;
                z3 = xb + (size_t)(bbase + 3) * TT * CC;
            }
            float acc0 = 0.f, acc1 = 0.f, acc2 = 0.f, acc3 = 0.f;
            #pragma unroll 4
            for (int kk = 0; kk < 256; kk += 4) {
                const float4 w4 = *(const float4*)(wrow + kk);
                const float4 a0 = *(const float4*)(z0 + kk);
                const float4 a1 = *(const float4*)(z1 + kk);
                const float4 a2 = *(const float4*)(z2 + kk);
                const float4 a3 = *(const float4*)(z3 + kk);
                acc0 = fmaf(w4.x,a0.x, fmaf(w4.y,a0.y, fmaf(w4.z,a0.z, fmaf(w4.w,a0.w, acc0))));
                acc1 = fmaf(w4.x,a1.x, fmaf(w4.y,a1.y, fmaf(w4.z,a1.z, fmaf(w4.w,a1.w, acc1))));
                acc2 = fmaf(w4.x,a2.x, fmaf(w4.y,a2.y, fmaf(w4.z,a2.z, fmaf(w4.w,a2.w, acc2))));
                acc3 = fmaf(w4.x,a3.x, fmaf(w4.y,a3.y, fmaf(w4.z,a3.z, fmaf(w4.w,a3.w, acc3))));
            }
            red[wv * 256 + (bbase + 0) * 8 + jlA] = acc0;
            red[wv * 256 + (bbase + 1) * 8 + jlA] = acc1;
            red[wv * 256 + (bbase + 2) * 8 + jlA] = acc2;
            red[wv * 256 + (bbase + 3) * 8 + jlA] = acc3;
        }
        __syncthreads();
        if (tid < 256) {   // reduce K-partials across the 8 waves; bias + gelu; store y
            const int b = tid >> 3;
            const int j = j0A + (tid & 7);
            float s = ba[j];
            #pragma unroll
            for (int w2 = 0; w2 < 8; ++w2) s += red[w2 * 256 + tid];
            y_ws[(size_t)b * CC2 + j] = gelu_exact(s);
        }
        gridbar(bar, ++ph);

        // ============ Phase B: y2[b][i] = sum_j y[b][j]*Wb[i][j] + bb[i] ==========
        {
            const int i = i0B + ilB;
            const float* wrow = Wb + (size_t)i * CC2 + wv * 256;
            const int bbase = blB * 2;
            const float* z0 = y_ws + (size_t)(bbase + 0) * CC2 + wv * 256;
            const float* z1 = y_ws + (size_t)(bbase + 1) * CC2 + wv * 256;
            float acc0 = 0.f, acc1 = 0.f;
            #pragma unroll 4
            for (int kk = 0; kk < 256; kk += 4) {
                const float4 w4 = *(const float4*)(wrow + kk);
                const float4 a0 = *(const float4*)(z0 + kk);
                const float4 a1 = *(const float4*)(z1 + kk);
                acc0 = fmaf(w4.x,a0.x, fmaf(w4.y,a0.y, fmaf(w4.z,a0.z, fmaf(w4.w,a0.w, acc0))));
                acc1 = fmaf(w4.x,a1.x, fmaf(w4.y,a1.y, fmaf(w4.z,a1.z, fmaf(w4.w,a1.w, acc1))));
            }
            red[wv * 128 + (bbase + 0) * 4 + ilB] = acc0;
            red[wv * 128 + (bbase + 1) * 4 + ilB] = acc1;
        }
        __syncthreads();
        if (tid < 128) {
            const int b = tid >> 2;
            const int i = i0B + (tid & 3);
            float s = bb[i];
            #pragma unroll
            for (int w2 = 0; w2 < 8; ++w2) s += red[w2 * 128 + tid];
            y2_ws[(size_t)b * CC + i] = s;
        }
        gridbar(bar, ++ph);

        // ============ Phase C: h = LN(y2)*gamma + beta + y2 ; out[b][t][:] = h ====
        if (blk < BB) {
            const int b = blk;
            const float* row = y2_ws + (size_t)b * CC;
            const int i = tid * 2;
            const float2 v = *(const float2*)(row + i);
            float s  = v.x + v.y;
            float ss = v.x * v.x + v.y * v.y;
            #pragma unroll
            for (int off = 32; off > 0; off >>= 1) {
                s  += __shfl_xor(s, off);
                ss += __shfl_xor(ss, off);
            }
            if (lane == 0) { redC[wv] = s; redC[8 + wv] = ss; }
            __syncthreads();
            float S = 0.f, SS = 0.f;
            #pragma unroll
            for (int w2 = 0; w2 < 8; ++w2) { S += redC[w2]; SS += redC[8 + w2]; }
            const float mu  = S * (1.0f / CC);
            const float var = SS * (1.0f / CC) - mu * mu;
            const float rs  = 1.0f / sqrtf(var + LNEPS);
            const float2 gm = *(const float2*)(gamma + i);
            const float2 bt = *(const float2*)(beta + i);
            const float h0 = (v.x - mu) * rs * gm.x + bt.x + v.x;
            const float h1 = (v.y - mu) * rs * gm.y + bt.y + v.y;
            *(float2*)(h_ws + (size_t)b * CC + i) = make_float2(h0, h1);
            *(float2*)(out + (size_t)b * TT * CC + (size_t)t * CC + i) = make_float2(h0, h1);
        }
        gridbar(bar, ++ph);
    }
}

extern "C" void kernel_launch(void* const* d_in, const int* in_sizes, int n_in,
                              void* d_out, int out_size, void* d_ws, size_t ws_size,
                              hipStream_t stream) {
    const float* x     = (const float*)d_in[0];
    const float* Wa    = (const float*)d_in[1];
    const float* ba    = (const float*)d_in[2];
    const float* Wb    = (const float*)d_in[3];
    const float* bb    = (const float*)d_in[4];
    const float* gamma = (const float*)d_in[5];
    const float* beta  = (const float*)d_in[6];
    float* out = (float*)d_out;
    float* ws  = (float*)d_ws;

    hipLaunchKernelGGL(rpe_init, dim3(64), dim3(512), 0, stream, ws);
    hipLaunchKernelGGL(rpe_main, dim3(NBLK), dim3(NTHR), 0, stream,
                       x, Wa, ba, Wb, bb, gamma, beta, out, ws);
}

// Round 2
// 144225.598 us; speedup vs baseline: 1.1671x; 1.1671x over previous
//
#include <hip/hip_runtime.h>
#include <math.h>

// Problem constants: B=32, T=1024, C=1024
#define CC    1024
#define CC2   2048
#define BB    32
#define TT    1024
#define NBLK  256      // persistent grid: 1 block/CU, all co-resident (barrier-safe)
#define NTHR  512      // 8 waves/block
#define LNEPS 1e-5f

// Workspace layout (float indices)
#define WS_H    0        // h state: 32*1024
#define WS_Y    32768    // y:       32*2048
#define WS_Y2   98304    // y2:      32*1024
#define WS_BARF 131072   // barrier uints (2048)

// LDS layout (float offsets within smem[17000], ~68 KB; gfx950 LDS = 160 KB)
// Phase A: zbuf @0      : 16 rows, off(r) = r*512 + (r>>2)*4   (extent 8204)
//          wbuf @8204   : 16 rows, off(j) = j*512 + (j>=8?4:0) (extent 8196)
// Phase B: ybuf @0      : 8 rows,  off(r) = r*512 + (r>>2)*4   (extent 4100)
//          wbuf2 @8192  : 16 rows, off(i) = i*512 + (i>>2)*4   (extent 8204)
// red (phase A): @0, [wv]*288 + [pos]*36 + a   (2304 floats, overlays dead zbuf)
// red (phase B): @0, [wv]*160 + [pos]*20 + a   (1280 floats, overlays dead ybuf)
// redC (phase C): @0..16
#define ZW_W  8204
#define WB2   8192

__global__ void rpe_init(float* __restrict__ ws) {
    unsigned* bar = (unsigned*)(ws + WS_BARF);
    for (int i = blockIdx.x * blockDim.x + threadIdx.x; i < 32768 + 2048;
         i += gridDim.x * blockDim.x) {
        if (i < 32768) ws[WS_H + i] = 0.0f;   // h0 = 0
        else           bar[i - 32768] = 0u;   // barrier counters (ws poisoned 0xAA)
    }
}

// Two-level monotonic grid barrier (proven in R1). 256 blocks: 32 leaf groups of 8.
__device__ __forceinline__ void gridbar(unsigned* bar, unsigned phase) {
    __syncthreads();
    if (threadIdx.x == 0) {
        __threadfence();  // release: write back this XCD's L2
        const unsigned g = (unsigned)blockIdx.x >> 3;
        unsigned v = __hip_atomic_fetch_add(&bar[g * 32u], 1u,
                        __ATOMIC_RELAXED, __HIP_MEMORY_SCOPE_AGENT) + 1u;
        if (v == phase * 8u) {
            unsigned r = __hip_atomic_fetch_add(&bar[1024], 1u,
                            __ATOMIC_RELAXED, __HIP_MEMORY_SCOPE_AGENT) + 1u;
            if (r == phase * 32u) {
                __hip_atomic_fetch_add(&bar[1056], 1u,
                    __ATOMIC_RELEASE, __HIP_MEMORY_SCOPE_AGENT);
            }
        }
        while (__hip_atomic_load(&bar[1056], __ATOMIC_RELAXED,
                                 __HIP_MEMORY_SCOPE_AGENT) < phase) {
            __builtin_amdgcn_s_sleep(2);
        }
    }
    __syncthreads();
    __threadfence();  // acquire: invalidate stale caches
}

__device__ __forceinline__ float gelu_exact(float a) {
    return 0.5f * a * (1.0f + erff(a * 0.70710678118654752440f));
}

// async global->LDS, 16 B per lane; LDS dst must be wave-uniform (HW adds lane*16)
__device__ __forceinline__ void async_cp16(const float* g, float* l) {
    __builtin_amdgcn_global_load_lds(
        (const __attribute__((address_space(1))) void*)g,
        (__attribute__((address_space(3))) void*)l, 16, 0, 0);
}

extern "C" __global__ void __launch_bounds__(NTHR)
rpe_main(const float* __restrict__ x,  const float* __restrict__ Wa,
         const float* __restrict__ ba, const float* __restrict__ Wb,
         const float* __restrict__ bbv, const float* __restrict__ gamma,
         const float* __restrict__ beta, float* __restrict__ out,
         float* __restrict__ ws)
{
    float*    h_ws  = ws + WS_H;
    float*    y_ws  = ws + WS_Y;
    float*    y2_ws = ws + WS_Y2;
    unsigned* bar   = (unsigned*)(ws + WS_BARF);

    const int tid  = threadIdx.x;
    const int blk  = blockIdx.x;
    const int wv   = tid >> 6;
    const int lane = tid & 63;
    const int pos  = lane & 7;      // lane-tile position within wave
    const int ks   = lane >> 3;     // in-wave k-segment (reduced via shfl_xor 8/16/32)

    __shared__ float smem[17000];   // 68 KB static (gfx950 supports up to 160 KB)

    // Phase A block tile: 128 j-groups x 2 b-groups
    const int j0  = (blk >> 1) * 16;
    const int b0A = (blk & 1) * 16;
    // Phase B block tile: 64 i-groups x 4 b-groups
    const int i0  = (blk >> 2) * 16;
    const int b0B = (blk & 3) * 8;

    const int jtA = pos & 1;   // j half   (8 j per lane)
    const int btA = pos >> 1;  // b quarter(4 b per lane)
    const int ipB = pos & 3;   // i quarter(4 i per lane)
    const int bpB = pos >> 2;  // b half   (4 b per lane)

    unsigned ph = 0;

    for (int t = 0; t < TT; ++t) {
        // ============ Phase A: y[b][j] = gelu(z @ Wa^T + ba), z=[h||x_t] ========
        float acc[32];
        #pragma unroll
        for (int a = 0; a < 32; ++a) acc[a] = 0.f;

        for (int c = 0; c < 4; ++c) {   // K chunks of 512 (c<2: h, c>=2: x_t)
            #pragma unroll
            for (int s = 0; s < 4; ++s) {   // z staging: 32 half-row issues
                const int q = wv * 4 + s;
                const int r = q >> 1, hf = q & 1;
                const float* g;
                if (c < 2) g = h_ws + (size_t)(b0A + r) * CC + c * 512 + hf * 256 + lane * 4;
                else       g = x + (size_t)(b0A + r) * TT * CC + (size_t)t * CC
                               + (c - 2) * 512 + hf * 256 + lane * 4;
                async_cp16(g, &smem[r * 512 + ((r >> 2) << 2) + hf * 256]);
            }
            #pragma unroll
            for (int s = 0; s < 4; ++s) {   // Wa staging: 32 half-row issues
                const int q = wv * 4 + s;
                const int jr = q >> 1, hf = q & 1;
                const float* g = Wa + (size_t)(j0 + jr) * CC2 + c * 512 + hf * 256 + lane * 4;
                async_cp16(g, &smem[ZW_W + jr * 512 + (jr >= 8 ? 4 : 0) + hf * 256]);
            }
            __syncthreads();   // drains vmcnt(0): staged data visible in LDS

            const int k0 = (wv * 8 + ks) * 8;
            #pragma unroll
            for (int kk = 0; kk < 8; kk += 4) {
                const int k = k0 + kk;
                float4 zz[4];
                #pragma unroll
                for (int b2 = 0; b2 < 4; ++b2)
                    zz[b2] = *(const float4*)&smem[(btA * 4 + b2) * 512 + btA * 4 + k];
                #pragma unroll
                for (int jj = 0; jj < 8; ++jj) {
                    const float4 ww = *(const float4*)&smem[ZW_W + (jtA * 8 + jj) * 512 + jtA * 4 + k];
                    #pragma unroll
                    for (int b2 = 0; b2 < 4; ++b2) {
                        const float4 zv = zz[b2];
                        float& A = acc[jj * 4 + b2];
                        A = fmaf(ww.x, zv.x, fmaf(ww.y, zv.y, fmaf(ww.z, zv.z, fmaf(ww.w, zv.w, A))));
                    }
                }
            }
            __syncthreads();   // LDS reads done before next chunk overwrites
        }
        // in-wave k reduction over ks (lane bits 3..5)
        #pragma unroll
        for (int a = 0; a < 32; ++a) {
            float v = acc[a];
            v += __shfl_xor(v, 8);
            v += __shfl_xor(v, 16);
            v += __shfl_xor(v, 32);
            acc[a] = v;
        }
        if (lane < 8) {   // lane==pos holds wave-partial; bank-padded stride 36
            #pragma unroll
            for (int a4 = 0; a4 < 32; a4 += 4)
                *(float4*)&smem[wv * 288 + lane * 36 + a4] =
                    make_float4(acc[a4], acc[a4 + 1], acc[a4 + 2], acc[a4 + 3]);
        }
        __syncthreads();
        if (tid < 256) {   // cross-wave combine; coalesced-ish y store (j fastest)
            const int bl = tid >> 4, jl = tid & 15;
            const int p2 = (bl >> 2) * 2 + (jl >> 3);
            const int a2 = (jl & 7) * 4 + (bl & 3);
            float s = ba[j0 + jl];
            #pragma unroll
            for (int w2 = 0; w2 < 8; ++w2) s += smem[w2 * 288 + p2 * 36 + a2];
            y_ws[(size_t)(b0A + bl) * CC2 + j0 + jl] = gelu_exact(s);
        }
        gridbar(bar, ++ph);

        // ============ Phase B: y2 = y @ Wb^T + bb ==============================
        float accB[16];
        #pragma unroll
        for (int a = 0; a < 16; ++a) accB[a] = 0.f;

        for (int c = 0; c < 4; ++c) {   // K (=j dim) chunks of 512
            #pragma unroll
            for (int s = 0; s < 6; ++s) {   // 16 y-issues + 32 Wb-issues
                const int q = wv * 6 + s;
                if (q < 16) {
                    const int r = q >> 1, hf = q & 1;
                    const float* g = y_ws + (size_t)(b0B + r) * CC2 + c * 512 + hf * 256 + lane * 4;
                    async_cp16(g, &smem[r * 512 + ((r >> 2) << 2) + hf * 256]);
                } else {
                    const int qq = q - 16;
                    const int ir = qq >> 1, hf = qq & 1;
                    const float* g = Wb + (size_t)(i0 + ir) * CC2 + c * 512 + hf * 256 + lane * 4;
                    async_cp16(g, &smem[WB2 + ir * 512 + ((ir >> 2) << 2) + hf * 256]);
                }
            }
            __syncthreads();

            const int k0 = (wv * 8 + ks) * 8;
            #pragma unroll
            for (int kk = 0; kk < 8; kk += 4) {
                const int k = k0 + kk;
                float4 yy[4];
                #pragma unroll
                for (int b2 = 0; b2 < 4; ++b2)
                    yy[b2] = *(const float4*)&smem[(bpB * 4 + b2) * 512 + bpB * 4 + k];
                #pragma unroll
                for (int ii = 0; ii < 4; ++ii) {
                    const float4 ww = *(const float4*)&smem[WB2 + (ipB * 4 + ii) * 512 + ipB * 4 + k];
                    #pragma unroll
                    for (int b2 = 0; b2 < 4; ++b2) {
                        const float4 yv = yy[b2];
                        float& A = accB[ii * 4 + b2];
                        A = fmaf(ww.x, yv.x, fmaf(ww.y, yv.y, fmaf(ww.z, yv.z, fmaf(ww.w, yv.w, A))));
                    }
                }
            }
            __syncthreads();
        }
        #pragma unroll
        for (int a = 0; a < 16; ++a) {
            float v = accB[a];
            v += __shfl_xor(v, 8);
            v += __shfl_xor(v, 16);
            v += __shfl_xor(v, 32);
            accB[a] = v;
        }
        if (lane < 8) {
            #pragma unroll
            for (int a4 = 0; a4 < 16; a4 += 4)
                *(float4*)&smem[wv * 160 + lane * 20 + a4] =
                    make_float4(accB[a4], accB[a4 + 1], accB[a4 + 2], accB[a4 + 3]);
        }
        __syncthreads();
        if (tid < 128) {
            const int bl = tid >> 4, il = tid & 15;
            const int p2 = (bl >> 2) * 4 + (il >> 2);
            const int a2 = (il & 3) * 4 + (bl & 3);
            float s = bbv[i0 + il];
            #pragma unroll
            for (int w2 = 0; w2 < 8; ++w2) s += smem[w2 * 160 + p2 * 20 + a2];
            y2_ws[(size_t)(b0B + bl) * CC + i0 + il] = s;
        }
        gridbar(bar, ++ph);

        // ============ Phase C: h = LN(y2)*gamma + beta + y2 ; out write ========
        if (blk < BB) {
            const int b = blk;
            const float* row = y2_ws + (size_t)b * CC;
            const int i = tid * 2;
            const float2 v = *(const float2*)(row + i);
            float s  = v.x + v.y;
            float ss = v.x * v.x + v.y * v.y;
            #pragma unroll
            for (int off = 32; off > 0; off >>= 1) {
                s  += __shfl_xor(s, off);
                ss += __shfl_xor(ss, off);
            }
            if (lane == 0) { smem[wv] = s; smem[8 + wv] = ss; }
            __syncthreads();
            float S = 0.f, SS = 0.f;
            #pragma unroll
            for (int w2 = 0; w2 < 8; ++w2) { S += smem[w2]; SS += smem[8 + w2]; }
            const float mu  = S * (1.0f / CC);
            const float var = SS * (1.0f / CC) - mu * mu;
            const float rs  = 1.0f / sqrtf(var + LNEPS);
            const float2 gm = *(const float2*)(gamma + i);
            const float2 bt = *(const float2*)(beta + i);
            const float h0 = (v.x - mu) * rs * gm.x + bt.x + v.x;
            const float h1 = (v.y - mu) * rs * gm.y + bt.y + v.y;
            *(float2*)(h_ws + (size_t)b * CC + i) = make_float2(h0, h1);
            *(float2*)(out + (size_t)b * TT * CC + (size_t)t * CC + i) = make_float2(h0, h1);
        }
        gridbar(bar, ++ph);
    }
}

extern "C" void kernel_launch(void* const* d_in, const int* in_sizes, int n_in,
                              void* d_out, int out_size, void* d_ws, size_t ws_size,
                              hipStream_t stream) {
    const float* x     = (const float*)d_in[0];
    const float* Wa    = (const float*)d_in[1];
    const float* ba    = (const float*)d_in[2];
    const float* Wb    = (const float*)d_in[3];
    const float* bb    = (const float*)d_in[4];
    const float* gamma = (const float*)d_in[5];
    const float* beta  = (const float*)d_in[6];
    float* out = (float*)d_out;
    float* ws  = (float*)d_ws;

    hipLaunchKernelGGL(rpe_init, dim3(64), dim3(512), 0, stream, ws);
    hipLaunchKernelGGL(rpe_main, dim3(NBLK), dim3(NTHR), 0, stream,
                       x, Wa, ba, Wb, bb, gamma, beta, out, ws);
}

// Round 4
// 42938.535 us; speedup vs baseline: 3.9202x; 3.3589x over previous
//
#include <hip/hip_runtime.h>
#include <math.h>

// Problem constants: B=32, T=1024, C=1024
#define CC    1024
#define CC2   2048
#define BB    32
#define TT    1024
#define NBLK  256      // persistent grid: 1 block/CU, all co-resident (barrier-safe)
#define NTHR  512      // 8 waves/block
#define LNEPS 1e-5f

// Workspace layout (float indices)
#define WS_H    0        // h state: 32*1024   (coherent: atomic stores / aux17 reads ONLY)
#define WS_Y    32768    // y:       32*2048   (coherent)
#define WS_Y2   98304    // y2:      32*1024   (coherent)
#define WS_BARF 131072   // barrier uints: root @1024, gen @1056

// LDS layout (float offsets in smem[17000], 68 KB)
#define ZW_W  8204
#define WB2   8192

// CPol aux bits (gfx950 / gfx94x family): bit0=SC0 (bypass L1), bit4=SC1 (bypass L2 -> LLC)
#define AUX_CACHED 0
#define AUX_COH    17

typedef float nfloat2 __attribute__((ext_vector_type(2)));  // native vec for nontemporal

__global__ void rpe_init(float* __restrict__ ws) {
    unsigned* bar = (unsigned*)(ws + WS_BARF);
    for (int i = blockIdx.x * blockDim.x + threadIdx.x; i < 32768 + 2048;
         i += gridDim.x * blockDim.x) {
        if (i < 32768) ws[WS_H + i] = 0.0f;   // h0 = 0 (dispatch-end release flushes L2)
        else           bar[i - 32768] = 0u;   // barrier counters (ws poisoned 0xAA)
    }
}

// Flat monotonic grid barrier. NO cache invalidation: exchanged data is coherent
// by construction (sc-bypass ops). Spin is an atomic RMW -> always served at LLC
// (a relaxed agent LOAD can be satisfied by the non-coherent XCD L2 -> stale spin;
// R1/R2's ~50us/barrier pathology).
__device__ __forceinline__ void gridbar(unsigned* bar, unsigned phase) {
    __threadfence_block();   // s_waitcnt vmcnt(0): this wave's stores retired (at LLC)
    __syncthreads();         // whole block done
    if (threadIdx.x == 0) {
        unsigned v = __hip_atomic_fetch_add(&bar[1024], 1u,
                        __ATOMIC_RELAXED, __HIP_MEMORY_SCOPE_AGENT) + 1u;
        if (v == phase * (unsigned)NBLK) {
            __hip_atomic_fetch_add(&bar[1056], 1u,
                __ATOMIC_RELEASE, __HIP_MEMORY_SCOPE_AGENT);
        }
        while (__hip_atomic_fetch_add(&bar[1056], 0u,
                    __ATOMIC_RELAXED, __HIP_MEMORY_SCOPE_AGENT) < phase) {
            __builtin_amdgcn_s_sleep(2);
        }
    }
    __syncthreads();
}

__device__ __forceinline__ float gelu_exact(float a) {
    return 0.5f * a * (1.0f + erff(a * 0.70710678118654752440f));
}

// async global->LDS, 16 B/lane. Cached variant for weights/x (L2-resident reuse).
__device__ __forceinline__ void async_cp16(const float* g, float* l) {
    __builtin_amdgcn_global_load_lds(
        (const __attribute__((address_space(1))) void*)g,
        (__attribute__((address_space(3))) void*)l, 16, 0, AUX_CACHED);
}
// Coherent variant for cross-block activations: SC0|SC1 -> read from LLC, no L2 allocate.
__device__ __forceinline__ void async_cp16_coh(const float* g, float* l) {
    __builtin_amdgcn_global_load_lds(
        (const __attribute__((address_space(1))) void*)g,
        (__attribute__((address_space(3))) void*)l, 16, 0, AUX_COH);
}

__device__ __forceinline__ void coh_store(float* p, float v) {
    __hip_atomic_store(p, v, __ATOMIC_RELAXED, __HIP_MEMORY_SCOPE_AGENT);
}
__device__ __forceinline__ float coh_load(const float* p) {
    return __hip_atomic_load(p, __ATOMIC_RELAXED, __HIP_MEMORY_SCOPE_AGENT);
}

extern "C" __global__ void __launch_bounds__(NTHR)
rpe_main(const float* __restrict__ x,  const float* __restrict__ Wa,
         const float* __restrict__ ba, const float* __restrict__ Wb,
         const float* __restrict__ bbv, const float* __restrict__ gamma,
         const float* __restrict__ beta, float* __restrict__ out,
         float* __restrict__ ws)
{
    float*    h_ws  = ws + WS_H;
    float*    y_ws  = ws + WS_Y;
    float*    y2_ws = ws + WS_Y2;
    unsigned* bar   = (unsigned*)(ws + WS_BARF);

    const int tid  = threadIdx.x;
    const int blk  = blockIdx.x;
    const int wv   = tid >> 6;
    const int lane = tid & 63;
    const int pos  = lane & 7;
    const int ks   = lane >> 3;

    __shared__ float smem[17000];

    const int j0  = (blk >> 1) * 16;     // Phase A: 128 j-groups x 2 b-groups
    const int b0A = (blk & 1) * 16;
    const int i0  = (blk >> 2) * 16;     // Phase B: 64 i-groups x 4 b-groups
    const int b0B = (blk & 3) * 8;

    const int jtA = pos & 1;
    const int btA = pos >> 1;
    const int ipB = pos & 3;
    const int bpB = pos >> 2;

    unsigned ph = 0;

    for (int t = 0; t < TT; ++t) {
        // ============ Phase A: y[b][j] = gelu(z @ Wa^T + ba), z=[h||x_t] ========
        float acc[32];
        #pragma unroll
        for (int a = 0; a < 32; ++a) acc[a] = 0.f;

        for (int c = 0; c < 4; ++c) {   // K chunks of 512 (c<2: h coherent, c>=2: x cached)
            #pragma unroll
            for (int s = 0; s < 4; ++s) {
                const int q = wv * 4 + s;
                const int r = q >> 1, hf = q & 1;
                float* ldst = &smem[r * 512 + ((r >> 2) << 2) + hf * 256];
                if (c < 2) {
                    const float* g = h_ws + (size_t)(b0A + r) * CC + c * 512 + hf * 256 + lane * 4;
                    async_cp16_coh(g, ldst);
                } else {
                    const float* g = x + (size_t)(b0A + r) * TT * CC + (size_t)t * CC
                                   + (c - 2) * 512 + hf * 256 + lane * 4;
                    async_cp16(g, ldst);
                }
            }
            #pragma unroll
            for (int s = 0; s < 4; ++s) {
                const int q = wv * 4 + s;
                const int jr = q >> 1, hf = q & 1;
                const float* g = Wa + (size_t)(j0 + jr) * CC2 + c * 512 + hf * 256 + lane * 4;
                async_cp16(g, &smem[ZW_W + jr * 512 + (jr >= 8 ? 4 : 0) + hf * 256]);
            }
            __syncthreads();   // vmcnt(0) drained: staged data visible in LDS

            const int k0 = (wv * 8 + ks) * 8;
            #pragma unroll
            for (int kk = 0; kk < 8; kk += 4) {
                const int k = k0 + kk;
                float4 zz[4];
                #pragma unroll
                for (int b2 = 0; b2 < 4; ++b2)
                    zz[b2] = *(const float4*)&smem[(btA * 4 + b2) * 512 + btA * 4 + k];
                #pragma unroll
                for (int jj = 0; jj < 8; ++jj) {
                    const float4 ww = *(const float4*)&smem[ZW_W + (jtA * 8 + jj) * 512 + jtA * 4 + k];
                    #pragma unroll
                    for (int b2 = 0; b2 < 4; ++b2) {
                        const float4 zv = zz[b2];
                        float& A = acc[jj * 4 + b2];
                        A = fmaf(ww.x, zv.x, fmaf(ww.y, zv.y, fmaf(ww.z, zv.z, fmaf(ww.w, zv.w, A))));
                    }
                }
            }
            __syncthreads();
        }
        #pragma unroll
        for (int a = 0; a < 32; ++a) {
            float v = acc[a];
            v += __shfl_xor(v, 8);
            v += __shfl_xor(v, 16);
            v += __shfl_xor(v, 32);
            acc[a] = v;
        }
        if (lane < 8) {
            #pragma unroll
            for (int a4 = 0; a4 < 32; a4 += 4)
                *(float4*)&smem[wv * 288 + lane * 36 + a4] =
                    make_float4(acc[a4], acc[a4 + 1], acc[a4 + 2], acc[a4 + 3]);
        }
        __syncthreads();
        if (tid < 256) {
            const int bl = tid >> 4, jl = tid & 15;
            const int p2 = (bl >> 2) * 2 + (jl >> 3);
            const int a2 = (jl & 7) * 4 + (bl & 3);
            float s = ba[j0 + jl];
            #pragma unroll
            for (int w2 = 0; w2 < 8; ++w2) s += smem[w2 * 288 + p2 * 36 + a2];
            coh_store(&y_ws[(size_t)(b0A + bl) * CC2 + j0 + jl], gelu_exact(s));
        }
        gridbar(bar, ++ph);

        // ============ Phase B: y2 = y @ Wb^T + bb ==============================
        float accB[16];
        #pragma unroll
        for (int a = 0; a < 16; ++a) accB[a] = 0.f;

        for (int c = 0; c < 4; ++c) {
            #pragma unroll
            for (int s = 0; s < 6; ++s) {
                const int q = wv * 6 + s;
                if (q < 16) {
                    const int r = q >> 1, hf = q & 1;
                    const float* g = y_ws + (size_t)(b0B + r) * CC2 + c * 512 + hf * 256 + lane * 4;
                    async_cp16_coh(g, &smem[r * 512 + ((r >> 2) << 2) + hf * 256]);
                } else {
                    const int qq = q - 16;
                    const int ir = qq >> 1, hf = qq & 1;
                    const float* g = Wb + (size_t)(i0 + ir) * CC2 + c * 512 + hf * 256 + lane * 4;
                    async_cp16(g, &smem[WB2 + ir * 512 + ((ir >> 2) << 2) + hf * 256]);
                }
            }
            __syncthreads();

            const int k0 = (wv * 8 + ks) * 8;
            #pragma unroll
            for (int kk = 0; kk < 8; kk += 4) {
                const int k = k0 + kk;
                float4 yy[4];
                #pragma unroll
                for (int b2 = 0; b2 < 4; ++b2)
                    yy[b2] = *(const float4*)&smem[(bpB * 4 + b2) * 512 + bpB * 4 + k];
                #pragma unroll
                for (int ii = 0; ii < 4; ++ii) {
                    const float4 ww = *(const float4*)&smem[WB2 + (ipB * 4 + ii) * 512 + ipB * 4 + k];
                    #pragma unroll
                    for (int b2 = 0; b2 < 4; ++b2) {
                        const float4 yv = yy[b2];
                        float& A = accB[ii * 4 + b2];
                        A = fmaf(ww.x, yv.x, fmaf(ww.y, yv.y, fmaf(ww.z, yv.z, fmaf(ww.w, yv.w, A))));
                    }
                }
            }
            __syncthreads();
        }
        #pragma unroll
        for (int a = 0; a < 16; ++a) {
            float v = accB[a];
            v += __shfl_xor(v, 8);
            v += __shfl_xor(v, 16);
            v += __shfl_xor(v, 32);
            accB[a] = v;
        }
        if (lane < 8) {
            #pragma unroll
            for (int a4 = 0; a4 < 16; a4 += 4)
                *(float4*)&smem[wv * 160 + lane * 20 + a4] =
                    make_float4(accB[a4], accB[a4 + 1], accB[a4 + 2], accB[a4 + 3]);
        }
        __syncthreads();
        if (tid < 128) {
            const int bl = tid >> 4, il = tid & 15;
            const int p2 = (bl >> 2) * 4 + (il >> 2);
            const int a2 = (il & 3) * 4 + (bl & 3);
            float s = bbv[i0 + il];
            #pragma unroll
            for (int w2 = 0; w2 < 8; ++w2) s += smem[w2 * 160 + p2 * 20 + a2];
            coh_store(&y2_ws[(size_t)(b0B + bl) * CC + i0 + il], s);
        }
        gridbar(bar, ++ph);

        // ============ Phase C: h = LN(y2)*gamma + beta + y2 ; out write ========
        if (blk < BB) {
            const int b = blk;
            const float* row = y2_ws + (size_t)b * CC;
            const int i = tid * 2;
            const float v0 = coh_load(row + i);
            const float v1 = coh_load(row + i + 1);
            float s  = v0 + v1;
            float ss = v0 * v0 + v1 * v1;
            #pragma unroll
            for (int off = 32; off > 0; off >>= 1) {
                s  += __shfl_xor(s, off);
                ss += __shfl_xor(ss, off);
            }
            if (lane == 0) { smem[wv] = s; smem[8 + wv] = ss; }
            __syncthreads();
            float S = 0.f, SS = 0.f;
            #pragma unroll
            for (int w2 = 0; w2 < 8; ++w2) { S += smem[w2]; SS += smem[8 + w2]; }
            const float mu  = S * (1.0f / CC);
            const float var = SS * (1.0f / CC) - mu * mu;
            const float rs  = 1.0f / sqrtf(var + LNEPS);
            const float2 gm = *(const float2*)(gamma + i);
            const float2 bt = *(const float2*)(beta + i);
            const float h0 = (v0 - mu) * rs * gm.x + bt.x + v0;
            const float h1 = (v1 - mu) * rs * gm.y + bt.y + v1;
            coh_store(&h_ws[(size_t)b * CC + i],     h0);
            coh_store(&h_ws[(size_t)b * CC + i + 1], h1);
            nfloat2 hv; hv.x = h0; hv.y = h1;
            __builtin_nontemporal_store(hv,
                (nfloat2*)(out + (size_t)b * TT * CC + (size_t)t * CC + i));
        }
        gridbar(bar, ++ph);
    }
}

extern "C" void kernel_launch(void* const* d_in, const int* in_sizes, int n_in,
                              void* d_out, int out_size, void* d_ws, size_t ws_size,
                              hipStream_t stream) {
    const float* x     = (const float*)d_in[0];
    const float* Wa    = (const float*)d_in[1];
    const float* ba    = (const float*)d_in[2];
    const float* Wb    = (const float*)d_in[3];
    const float* bb    = (const float*)d_in[4];
    const float* gamma = (const float*)d_in[5];
    const float* beta  = (const float*)d_in[6];
    float* out = (float*)d_out;
    float* ws  = (float*)d_ws;

    hipLaunchKernelGGL(rpe_init, dim3(64), dim3(512), 0, stream, ws);
    hipLaunchKernelGGL(rpe_main, dim3(NBLK), dim3(NTHR), 0, stream,
                       x, Wa, ba, Wb, bb, gamma, beta, out, ws);
}